// Round 5
// baseline (418.692 us; speedup 1.0000x reference)
//
#include <hip/hip_runtime.h>
#include <stdint.h>
#include <math.h>

#define NEGV -1.0e12f
// Q pre-scale: 1/sqrt(64) * log2(e)  (softmax uses native exp2)
#define QSCALE 0.18033688011112042f

typedef __attribute__((ext_vector_type(8))) short bf16x8;
typedef __attribute__((ext_vector_type(4))) float f32x4;
typedef __attribute__((ext_vector_type(8))) ushort u16x8;

// guaranteed 1-instruction rotate: rotl(v,r) = alignbit(v,v,32-r); 32-r <= 64 -> inline const
#define ROTL1(v, r) ({ uint32_t _d;                                            \
    asm("v_alignbit_b32 %0, %1, %1, %2" : "=v"(_d) : "v"(v), "n"(32 - (r)));   \
    _d; })

// ---------------- Threefry-2x32/20, host reference (key derivation) ----------------
__host__ static void tf2x32_host(uint32_t k0, uint32_t k1, uint32_t c0, uint32_t c1,
                                 uint32_t* o0, uint32_t* o1) {
    uint32_t ks2 = k0 ^ k1 ^ 0x1BD11BDAu;
    uint32_t x0 = c0 + k0, x1 = c1 + k1;
#define TF_RND(r) x0 += x1; x1 = ((x1 << (r)) | (x1 >> (32 - (r)))); x1 ^= x0;
    TF_RND(13) TF_RND(15) TF_RND(26) TF_RND(6)
    x0 += k1;  x1 += ks2 + 1u;
    TF_RND(17) TF_RND(29) TF_RND(16) TF_RND(24)
    x0 += ks2; x1 += k0 + 2u;
    TF_RND(13) TF_RND(15) TF_RND(26) TF_RND(6)
    x0 += k0;  x1 += k1 + 3u;
    TF_RND(17) TF_RND(29) TF_RND(16) TF_RND(24)
    x0 += k1;  x1 += ks2 + 4u;
    TF_RND(13) TF_RND(15) TF_RND(26) TF_RND(6)
    x0 += ks2; x1 += k0 + 5u;
#undef TF_RND
    *o0 = x0; *o1 = x1;
}

// device: JAX partitionable random bits for counter (0, j): bits = o0 ^ o1
__device__ __forceinline__ uint32_t tf_bits(uint32_t k0, uint32_t k1, uint32_t j) {
    const uint32_t ks2 = k0 ^ k1 ^ 0x1BD11BDAu;
    uint32_t x0 = k0, x1 = j + k1;
#define TFR(r) x0 += x1; x1 = ROTL1(x1, r); x1 ^= x0;
    TFR(13) TFR(15) TFR(26) TFR(6)
    x0 += k1;  x1 += ks2 + 1u;
    TFR(17) TFR(29) TFR(16) TFR(24)
    x0 += ks2; x1 += k0 + 2u;
    TFR(13) TFR(15) TFR(26) TFR(6)
    x0 += k0;  x1 += k1 + 3u;
    TFR(17) TFR(29) TFR(16) TFR(24)
    x0 += k1;  x1 += ks2 + 4u;
    TFR(13) TFR(15) TFR(26) TFR(6)
#undef TFR
    return (x0 + ks2) ^ (x1 + (k0 + 5u));
}

// bernoulli(p) true  <=>  bits < T,  T = ceil(p * 2^23) << 9  (exact vs JAX float path)
__host__ static uint32_t maskT(float p) {
    double t = ceil((double)p * 8388608.0);
    return ((uint32_t)t) << 9;
}

__device__ __forceinline__ ushort f2bf(float x) {
    uint32_t u = __float_as_uint(x);
    u += 0x7fffu + ((u >> 16) & 1u);
    return (ushort)(u >> 16);
}

// ---------------- x transpose+convert: x[b][c][n] fp32 -> xt[b*1024+n][c] bf16 -------
__global__ __launch_bounds__(256) void xpose_k(const float* __restrict__ x,
                                               ushort* __restrict__ xt)
{
    __shared__ float tile[64][65];
    const int tid = threadIdx.x;
    const int b = blockIdx.z, c0 = blockIdx.y * 64, n0 = blockIdx.x * 64;
    const float* src = x + ((size_t)b * 512 + c0) * 1024 + n0;
#pragma unroll
    for (int i = 0; i < 4; ++i) {
        const int r = (tid >> 4) + i * 16;
        const int col = (tid & 15) * 4;
        float4 v = *(const float4*)(src + (size_t)r * 1024 + col);
        tile[r][col + 0] = v.x; tile[r][col + 1] = v.y;
        tile[r][col + 2] = v.z; tile[r][col + 3] = v.w;
    }
    __syncthreads();
#pragma unroll
    for (int i = 0; i < 2; ++i) {
        const int nl = (tid >> 3) + i * 32;
        const int cb = (tid & 7) * 8;
        u16x8 o;
#pragma unroll
        for (int j = 0; j < 8; ++j) o[j] = f2bf(tile[cb + j][nl]);
        *(u16x8*)(xt + ((size_t)b * 1024 + n0 + nl) * 512 + c0 + cb) = o;
    }
}

// ---------------- weight convert fp32 -> bf16 (5 regions packed) ----------------
__global__ __launch_bounds__(256) void wcvt_k(const float* __restrict__ s0,
                                              const float* __restrict__ s1,
                                              const float* __restrict__ s2,
                                              const float* __restrict__ s3,
                                              const float* __restrict__ s4,
                                              ushort* __restrict__ dst)
{
    const size_t i = ((size_t)blockIdx.x * 256 + threadIdx.x) * 8;
    const float* src; size_t off;
    if (i < 262144)       { src = s0; off = 0; }
    else if (i < 1048576) { src = s1; off = 262144; }
    else if (i < 1310720) { src = s2; off = 1048576; }
    else if (i < 1572864) { src = s3; off = 1310720; }
    else                  { src = s4; off = 1572864; }
    const float* p = src + (i - off);
    float4 a = *(const float4*)p;
    float4 b = *(const float4*)(p + 4);
    u16x8 o;
    o[0] = f2bf(a.x); o[1] = f2bf(a.y); o[2] = f2bf(a.z); o[3] = f2bf(a.w);
    o[4] = f2bf(b.x); o[5] = f2bf(b.y); o[6] = f2bf(b.z); o[7] = f2bf(b.w);
    *(u16x8*)(dst + i) = o;
}

// ---------------- bf16 MFMA GEMM: C[m][o] = sum_k A[m][k]*W[o][k] + bias[o] ---------
// A [M][512] bf16, W [O][512] bf16. Block = 4 waves stacked in m; wave tile RWx64.
// EPI 0: fp32 store  1: qkv scatter (natural layouts)  2: gelu+m1 -> bf16
// EPI 3: m2 -> fp32  4: bf16 store
template<int RW, int EPI>
__global__ __launch_bounds__(256) void bgemm_k(
    const ushort* __restrict__ A, const ushort* __restrict__ W,
    const float* __restrict__ bias, float* __restrict__ outf,
    ushort* __restrict__ outb,
    ushort* __restrict__ qb, ushort* __restrict__ kb, ushort* __restrict__ vb,
    uint32_t mkk0, uint32_t mkk1, uint32_t T)
{
    constexpr int NF = RW / 16;
    const int tid = threadIdx.x;
    const int wave = tid >> 6, lane = tid & 63;
    const int lg = lane >> 4, lc = lane & 15;
    const int m0 = blockIdx.x * (4 * RW) + wave * RW;
    const int o0 = blockIdx.y * 64;

    f32x4 acc[NF][4];
#pragma unroll
    for (int i = 0; i < NF; ++i)
#pragma unroll
        for (int j = 0; j < 4; ++j) acc[i][j] = (f32x4){0.f, 0.f, 0.f, 0.f};

    const ushort* Ab = A + (size_t)(m0 + lc) * 512 + lg * 8;
    const ushort* Wb = W + (size_t)(o0 + lc) * 512 + lg * 8;

#pragma unroll 2
    for (int k0 = 0; k0 < 512; k0 += 32) {
        bf16x8 aq[NF], bw[4];
#pragma unroll
        for (int i = 0; i < NF; ++i) aq[i] = *(const bf16x8*)(Ab + (size_t)i * 16 * 512 + k0);
#pragma unroll
        for (int j = 0; j < 4; ++j) bw[j] = *(const bf16x8*)(Wb + (size_t)j * 16 * 512 + k0);
#pragma unroll
        for (int i = 0; i < NF; ++i)
#pragma unroll
            for (int j = 0; j < 4; ++j)
                acc[i][j] = __builtin_amdgcn_mfma_f32_16x16x32_bf16(aq[i], bw[j], acc[i][j], 0, 0, 0);
    }

    float bvv[4];
#pragma unroll
    for (int j = 0; j < 4; ++j) bvv[j] = bias[o0 + j * 16 + lc];

#pragma unroll
    for (int i = 0; i < NF; ++i) {
#pragma unroll
        for (int j = 0; j < 4; ++j) {
#pragma unroll
            for (int r = 0; r < 4; ++r) {
                const int m = m0 + i * 16 + lg * 4 + r;
                const int o = o0 + j * 16 + lc;
                float v = acc[i][j][r] + bvv[j];
                if constexpr (EPI == 0) {
                    outf[(size_t)m * 512 + o] = v;
                } else if constexpr (EPI == 4) {
                    outb[(size_t)m * 512 + o] = f2bf(v);
                } else if constexpr (EPI == 2) {
                    v = 0.5f * v * (1.0f + erff(v * 0.70710678118654752f));
                    if (tf_bits(mkk0, mkk1, (uint32_t)(m * 512 + o)) < T) v += NEGV;
                    outb[(size_t)m * 512 + o] = f2bf(v);
                } else if constexpr (EPI == 3) {
                    if (tf_bits(mkk0, mkk1, (uint32_t)(m * 512 + o)) < T) v += NEGV;
                    outf[(size_t)m * 512 + o] = v;
                } else {  // EPI == 1: qkv scatter, all-natural layouts
                    const int s = o >> 9, hh = (o >> 6) & 7, d = o & 63;
                    const int b = m >> 10, n = m & 1023;
                    const int bh = b * 8 + hh;
                    ushort* dst = (s == 0) ? qb : (s == 1) ? kb : vb;
                    const float scl = (s == 0) ? QSCALE : 1.0f;
                    dst[((size_t)bh * 1024 + n) * 64 + d] = f2bf(v * scl);
                }
            }
        }
    }
}

// ---------------- V transpose: v[bh][n][64] -> vt[bh][d][n], LDS tiled ----------------
__global__ __launch_bounds__(256) void vxpose_k(const ushort* __restrict__ v,
                                                ushort* __restrict__ vt)
{
    __shared__ ushort tile[64][72];
    const int tid = threadIdx.x;
    const int bh = blockIdx.y, n0 = blockIdx.x * 64;
    const int row = tid >> 2, cq = (tid & 3) * 16;
    const ushort* src = v + ((size_t)bh * 1024 + n0 + row) * 64 + cq;
    *(u16x8*)&tile[row][cq] = *(const u16x8*)src;
    *(u16x8*)&tile[row][cq + 8] = *(const u16x8*)(src + 8);
    __syncthreads();
    const int d = tid >> 2, nq = (tid & 3) * 16;
    u16x8 o0v, o1v;
#pragma unroll
    for (int i = 0; i < 8; ++i) o0v[i] = tile[nq + i][d];
#pragma unroll
    for (int i = 0; i < 8; ++i) o1v[i] = tile[nq + 8 + i][d];
    ushort* dst = vt + ((size_t)bh * 64 + d) * 1024 + n0 + nq;
    *(u16x8*)dst = o0v;
    *(u16x8*)(dst + 8) = o1v;
}

// ---------------- LayerNorm (LN1): one wave per token -> bf16 out ----------------
__global__ __launch_bounds__(256) void ln_k(const float* __restrict__ in,
                                            const float* __restrict__ g,
                                            const float* __restrict__ bb,
                                            ushort* __restrict__ outb)
{
    const int wave = threadIdx.x >> 6, lane = threadIdx.x & 63;
    const size_t tok = (size_t)blockIdx.x * 4 + wave;
    const float* row = in + tok * 512;
    const int c0 = lane * 8;
    float4 v0 = *(const float4*)(row + c0);
    float4 v1 = *(const float4*)(row + c0 + 4);
    float x[8] = {v0.x, v0.y, v0.z, v0.w, v1.x, v1.y, v1.z, v1.w};
    float s = 0.f;
#pragma unroll
    for (int i = 0; i < 8; i++) s += x[i];
#pragma unroll
    for (int sh = 32; sh; sh >>= 1) s += __shfl_xor(s, sh, 64);
    const float mu = s * (1.0f / 512.0f);
    float vsum = 0.f;
#pragma unroll
    for (int i = 0; i < 8; i++) { float d = x[i] - mu; vsum += d * d; }
#pragma unroll
    for (int sh = 32; sh; sh >>= 1) vsum += __shfl_xor(vsum, sh, 64);
    const float inv = 1.0f / sqrtf(vsum * (1.0f / 512.0f) + 1e-5f);
    float4 g0 = *(const float4*)(g + c0);
    float4 g1 = *(const float4*)(g + c0 + 4);
    float4 b0 = *(const float4*)(bb + c0);
    float4 b1 = *(const float4*)(bb + c0 + 4);
    float gg[8] = {g0.x, g0.y, g0.z, g0.w, g1.x, g1.y, g1.z, g1.w};
    float bv[8] = {b0.x, b0.y, b0.z, b0.w, b1.x, b1.y, b1.z, b1.w};
    u16x8 o;
#pragma unroll
    for (int i = 0; i < 8; i++) o[i] = f2bf((x[i] - mu) * inv * gg[i] + bv[i]);
    *(u16x8*)(outb + tok * 512 + c0) = o;
}

// ---------------- LN2 + token-partial-sum fused ----------------
// grid 2048: block = 4 tokens of one batch; writes pblock[block][512] (sum of 4 LN rows)
__global__ __launch_bounds__(256) void ln2mean_k(const float* __restrict__ in,
                                                 const float* __restrict__ g,
                                                 const float* __restrict__ bb,
                                                 float* __restrict__ pblock)
{
    __shared__ float rows[4][512];
    const int wave = threadIdx.x >> 6, lane = threadIdx.x & 63;
    const int b = blockIdx.x >> 8;
    const size_t tok = (size_t)b * 1024 + (blockIdx.x & 255) * 4 + wave;
    const float* row = in + tok * 512;
    const int c0 = lane * 8;
    float4 v0 = *(const float4*)(row + c0);
    float4 v1 = *(const float4*)(row + c0 + 4);
    float x[8] = {v0.x, v0.y, v0.z, v0.w, v1.x, v1.y, v1.z, v1.w};
    float s = 0.f;
#pragma unroll
    for (int i = 0; i < 8; i++) s += x[i];
#pragma unroll
    for (int sh = 32; sh; sh >>= 1) s += __shfl_xor(s, sh, 64);
    const float mu = s * (1.0f / 512.0f);
    float vsum = 0.f;
#pragma unroll
    for (int i = 0; i < 8; i++) { float d = x[i] - mu; vsum += d * d; }
#pragma unroll
    for (int sh = 32; sh; sh >>= 1) vsum += __shfl_xor(vsum, sh, 64);
    const float inv = 1.0f / sqrtf(vsum * (1.0f / 512.0f) + 1e-5f);
    float4 g0 = *(const float4*)(g + c0);
    float4 g1 = *(const float4*)(g + c0 + 4);
    float4 b0 = *(const float4*)(bb + c0);
    float4 b1 = *(const float4*)(bb + c0 + 4);
    float gg[8] = {g0.x, g0.y, g0.z, g0.w, g1.x, g1.y, g1.z, g1.w};
    float bv[8] = {b0.x, b0.y, b0.z, b0.w, b1.x, b1.y, b1.z, b1.w};
    float o[8];
#pragma unroll
    for (int i = 0; i < 8; i++) o[i] = (x[i] - mu) * inv * gg[i] + bv[i];
    *(float4*)&rows[wave][c0]     = make_float4(o[0], o[1], o[2], o[3]);
    *(float4*)&rows[wave][c0 + 4] = make_float4(o[4], o[5], o[6], o[7]);
    __syncthreads();
    const int c = threadIdx.x;
    float p0 = rows[0][c] + rows[1][c] + rows[2][c] + rows[3][c];
    float p1 = rows[0][c + 256] + rows[1][c + 256] + rows[2][c + 256] + rows[3][c + 256];
    pblock[(size_t)blockIdx.x * 512 + c] = p0;
    pblock[(size_t)blockIdx.x * 512 + c + 256] = p1;
}

// reduce pblock -> tm[b][c] (mean over 1024 tokens)
__global__ __launch_bounds__(256) void mred_k(const float* __restrict__ pblock,
                                              float* __restrict__ tm)
{
    __shared__ float red[8][33];
    const int c0 = blockIdx.x * 32, b = blockIdx.y;
    const int cl = threadIdx.x & 31, jg = threadIdx.x >> 5;
    const float* p = pblock + ((size_t)b * 256 + jg * 32) * 512 + c0 + cl;
    float s = 0.f;
#pragma unroll 8
    for (int j = 0; j < 32; ++j) s += p[(size_t)j * 512];
    red[jg][cl] = s;
    __syncthreads();
    if (jg == 0) {
        float t = 0.f;
#pragma unroll
        for (int g2 = 0; g2 < 8; ++g2) t += red[g2][cl];
        tm[b * 512 + c0 + cl] = t * (1.0f / 1024.0f);
    }
}

// ---------------- MFMA bf16 flash attention PASS1: half the keys per block ----------
// grid (16, 64, 2). 4 waves; wave owns 16 q rows; fixed-max softmax in exp2 domain.
// Writes unnormalized O (fp32) and D partials.
__global__ __launch_bounds__(256) void attn_p1(
    const ushort* __restrict__ qb, const ushort* __restrict__ kb,
    const ushort* __restrict__ vtb, float* __restrict__ Ou, float* __restrict__ Du,
    uint32_t km0, uint32_t km1)
{
    __shared__ ushort plds[4][16][40];
    const int tid = threadIdx.x;
    const int wave = tid >> 6, lane = tid & 63;
    const int bh = blockIdx.y, kh = blockIdx.z;
    const int q0 = blockIdx.x * 64 + wave * 16;
    const int lg = lane >> 4, lc = lane & 15;
    const int koff = kh * 512;

    const ushort* qp = qb + (size_t)bh * 65536;

    bf16x8 aq0 = *(const bf16x8*)(qp + (size_t)(q0 + lc) * 64 + lg * 8);
    bf16x8 aq1 = *(const bf16x8*)(qp + (size_t)(q0 + lc) * 64 + 32 + lg * 8);

    f32x4 zero = {0.f, 0.f, 0.f, 0.f};
    f32x4 oacc[4] = {zero, zero, zero, zero};
    float D[4] = {0.f, 0.f, 0.f, 0.f};

    uint32_t jr[4];
#pragma unroll
    for (int r = 0; r < 4; ++r)
        jr[r] = ((uint32_t)bh * 1024u + (uint32_t)(q0 + lg * 4 + r)) * 1024u
              + (uint32_t)(koff + lc);

    const ushort* krow = kb + (size_t)bh * 65536 + (size_t)(koff + lc) * 64 + lg * 8;
    const ushort* vrow = vtb + (size_t)bh * 65536 + (size_t)lc * 1024 + koff + lg * 8;

    for (int ch = 0; ch < 16; ++ch) {
        bf16x8 bk00 = *(const bf16x8*)(krow);
        bf16x8 bk01 = *(const bf16x8*)(krow + 32);
        bf16x8 bk10 = *(const bf16x8*)(krow + 1024);
        bf16x8 bk11 = *(const bf16x8*)(krow + 1056);

        f32x4 s0 = __builtin_amdgcn_mfma_f32_16x16x32_bf16(aq0, bk00, zero, 0, 0, 0);
        s0 = __builtin_amdgcn_mfma_f32_16x16x32_bf16(aq1, bk01, s0, 0, 0, 0);
        f32x4 s1 = __builtin_amdgcn_mfma_f32_16x16x32_bf16(aq0, bk10, zero, 0, 0, 0);
        s1 = __builtin_amdgcn_mfma_f32_16x16x32_bf16(aq1, bk11, s1, 0, 0, 0);

#pragma unroll
        for (int r = 0; r < 4; ++r) {
            const uint32_t bits0 = tf_bits(km0, km1, jr[r]);
            const uint32_t bits1 = tf_bits(km0, km1, jr[r] + 16u);
            jr[r] += 32u;
            const float pv0 = ((int)bits0 < 0) ? exp2f(s0[r]) : 0.f;
            const float pv1 = ((int)bits1 < 0) ? exp2f(s1[r]) : 0.f;
            D[r] += pv0 + pv1;
            uint32_t pk;
            asm("v_cvt_pk_bf16_f32 %0, %1, %2" : "=v"(pk) : "v"(pv0), "v"(pv1));
            plds[wave][lg * 4 + r][lc] = (ushort)pk;
            plds[wave][lg * 4 + r][lc + 16] = (ushort)(pk >> 16);
        }

        bf16x8 pa = *(const bf16x8*)&plds[wave][lc][lg * 8];

#pragma unroll
        for (int dt = 0; dt < 4; ++dt) {
            bf16x8 bv = *(const bf16x8*)(vrow + (size_t)dt * 16384);
            oacc[dt] = __builtin_amdgcn_mfma_f32_16x16x32_bf16(pa, bv, oacc[dt], 0, 0, 0);
        }
        krow += 2048;
        vrow += 32;
    }

#pragma unroll
    for (int r = 0; r < 4; ++r) {
#pragma unroll
        for (int sh = 1; sh < 16; sh <<= 1) D[r] += __shfl_xor(D[r], sh, 64);
    }

    const size_t obase = ((size_t)kh * 64 + bh) * 1024;
#pragma unroll
    for (int r = 0; r < 4; ++r) {
        const int q = q0 + lg * 4 + r;
        if (lc == 0) Du[obase + q] = D[r];
#pragma unroll
        for (int dt = 0; dt < 4; ++dt)
            Ou[(obase + q) * 64 + dt * 16 + lc] = oacc[dt][r];
    }
}

// ---------------- PASS2: combine key-halves, normalize, write bf16 O ----------------
__global__ __launch_bounds__(256) void attn_p2(const float* __restrict__ Ou,
                                               const float* __restrict__ Du,
                                               ushort* __restrict__ ob)
{
    const uint32_t idx = blockIdx.x * 256 + threadIdx.x;  // 1,048,576 total
    const int d = (idx & 15) * 4;
    const int q = (idx >> 4) & 1023;
    const int bh = idx >> 14;
    const size_t base = ((size_t)bh * 1024 + q) * 64 + d;
    float4 a = *(const float4*)(Ou + base);
    float4 c = *(const float4*)(Ou + base + 4194304);
    const float Dv = Du[bh * 1024 + q] + Du[bh * 1024 + q + 65536];
    const float inv = 1.0f / Dv;
    ushort4 o;
    o.x = f2bf((a.x + c.x) * inv);
    o.y = f2bf((a.y + c.y) * inv);
    o.z = f2bf((a.z + c.z) * inv);
    o.w = f2bf((a.w + c.w) * inv);
    const int b = bh >> 3, h = bh & 7;
    *(ushort4*)(ob + ((size_t)(b * 1024 + q)) * 512 + h * 64 + d) = o;
}

// ---------------- final fc ----------------
__global__ __launch_bounds__(256) void fc_k(const float* __restrict__ tm,
                                            const float* __restrict__ w,
                                            const float* __restrict__ bias,
                                            float* __restrict__ outp)
{
    const int b = blockIdx.y;
    const int o = blockIdx.x * 256 + threadIdx.x;
    const float* tr = tm + b * 512;
    const float* wr = w + (size_t)o * 512;
    float s = 0.f;
    for (int k = 0; k < 512; k += 4) {
        float4 a = *(const float4*)(tr + k);
        float4 ww = *(const float4*)(wr + k);
        s = fmaf(a.x, ww.x, s); s = fmaf(a.y, ww.y, s);
        s = fmaf(a.z, ww.z, s); s = fmaf(a.w, ww.w, s);
    }
    outp[b * 2560 + o] = s + bias[o];
}

// ---------------- launch ----------------
extern "C" void kernel_launch(void* const* d_in, const int* in_sizes, int n_in,
                              void* d_out, int out_size, void* d_ws, size_t ws_size,
                              hipStream_t stream)
{
    const float* x      = (const float*)d_in[0];
    const float* conv_w = (const float*)d_in[1];
    const float* conv_b = (const float*)d_in[2];
    const float* ln_g   = (const float*)d_in[3];
    const float* ln_b   = (const float*)d_in[4];
    const float* qkv_w  = (const float*)d_in[5];
    const float* qkv_b  = (const float*)d_in[6];
    const float* proj_w = (const float*)d_in[7];
    const float* proj_b = (const float*)d_in[8];
    const float* w1     = (const float*)d_in[9];
    const float* b1     = (const float*)d_in[10];
    const float* w2     = (const float*)d_in[11];
    const float* b2     = (const float*)d_in[12];
    const float* fc_w   = (const float*)d_in[13];
    const float* fc_b   = (const float*)d_in[14];
    float* out = (float*)d_out;

    if (ws_size < (size_t)83886080) return;  // need 80 MiB scratch

    uint32_t mk0a, mk0b, mk1a, mk1b, mk2a, mk2b;
    tf2x32_host(0u, 42u, 0u, 0u, &mk0a, &mk0b);
    tf2x32_host(0u, 42u, 0u, 1u, &mk1a, &mk1b);
    tf2x32_host(0u, 42u, 0u, 2u, &mk2a, &mk2b);
    const uint32_t T_m1 = maskT(0.3f);
    const uint32_t T_m2 = maskT(0.1f);

    char* wsb = (char*)d_ws;
    ushort* xt     = (ushort*)wsb;                   // 8 MiB @0      -> obuf
    ushort* wts    = (ushort*)(wsb + 8388608);       // 3.5MiB @8M
    ushort* qbuf   = (ushort*)(wsb + 12582912);      // 8 MiB @12M    -> hbuf
    ushort* kbuf   = (ushort*)(wsb + 20971520);      // 8 MiB @20M    -> pblock+tm
    ushort* vbuf   = (ushort*)(wsb + 29360128);      // 8 MiB @28M
    ushort* vtbuf  = (ushort*)(wsb + 37748736);      // 8 MiB @36M
    float*  tC     = (float*)(wsb + 46137344);       // 16 MiB @44M   -> Ou(32M) -> t2
    ushort* tCbf   = (ushort*)(wsb + 62914560);      // 8 MiB @60M    -> projbf
    float*  Ou     = (float*)(wsb + 46137344);       // 32 MiB @44M (attn only)
    float*  Du     = (float*)(wsb + 79691776);       // 512 KiB @76M
    ushort* obuf   = xt;
    ushort* projbf = tCbf;
    ushort* hbuf   = qbuf;
    float*  t2     = tC;
    float*  pblock = (float*)(wsb + 20971520);       // 4 MiB
    float*  tm     = (float*)(wsb + 25165824);       // 16 KiB

    ushort* wconv = wts;
    ushort* wqkv  = wts + 262144;
    ushort* wproj = wts + 1048576;
    ushort* ww1   = wts + 1310720;
    ushort* ww2   = wts + 1572864;

    dim3 blk(256);
    // x -> xt bf16 [8192][512]
    xpose_k<<<dim3(16, 8, 8), blk, 0, stream>>>(x, xt);
    // weights -> bf16
    wcvt_k<<<dim3(896), blk, 0, stream>>>(conv_w, qkv_w, proj_w, w1, w2, wts);
    // conv -> tC fp32  (16x64 wave tile, 16 waves/CU)
    bgemm_k<16, 0><<<dim3(128, 8), blk, 0, stream>>>(xt, wconv, conv_b, tC, nullptr,
                                                     nullptr, nullptr, nullptr, 0u, 0u, 0u);
    // LN1 -> tCbf bf16
    ln_k<<<dim3(2048), blk, 0, stream>>>(tC, ln_g, ln_b, tCbf);
    // qkv -> q (exp2-prescaled) / k / v natural bf16  (32x64 wave, 24 waves/CU)
    bgemm_k<32, 1><<<dim3(64, 24), blk, 0, stream>>>(tCbf, wqkv, qkv_b, nullptr, nullptr,
                                                     qbuf, kbuf, vbuf, 0u, 0u, 0u);
    // v -> vt
    vxpose_k<<<dim3(16, 64), blk, 0, stream>>>(vbuf, vtbuf);
    // attention pass1 (key-split x2) -> Ou, Du
    attn_p1<<<dim3(16, 64, 2), blk, 0, stream>>>(qbuf, kbuf, vtbuf, Ou, Du, mk0a, mk0b);
    // pass2 combine -> obuf bf16
    attn_p2<<<dim3(4096), blk, 0, stream>>>(Ou, Du, obuf);
    // proj -> projbf bf16
    bgemm_k<16, 4><<<dim3(128, 8), blk, 0, stream>>>(obuf, wproj, proj_b, nullptr, projbf,
                                                     nullptr, nullptr, nullptr, 0u, 0u, 0u);
    // w1 + gelu + m1 -> hbuf bf16
    bgemm_k<16, 2><<<dim3(128, 8), blk, 0, stream>>>(projbf, ww1, b1, nullptr, hbuf,
                                                     nullptr, nullptr, nullptr, mk1a, mk1b, T_m1);
    // w2 + m2 -> t2 fp32
    bgemm_k<16, 3><<<dim3(128, 8), blk, 0, stream>>>(hbuf, ww2, b2, t2, nullptr,
                                                     nullptr, nullptr, nullptr, mk2a, mk2b, T_m2);
    // LN2 + token partial sums
    ln2mean_k<<<dim3(2048), blk, 0, stream>>>(t2, ln_g, ln_b, pblock);
    // reduce partials -> tm
    mred_k<<<dim3(16, 8), blk, 0, stream>>>(pblock, tm);
    // fc -> out
    fc_k<<<dim3(10, 8), blk, 0, stream>>>(tm, fc_w, fc_b, out);
}